// Round 9
// baseline (58.803 us; speedup 1.0000x reference)
//
#include <hip/hip_runtime.h>

typedef unsigned short u16;
typedef unsigned int u32;
typedef float f32x4 __attribute__((ext_vector_type(4)));
typedef short s16x8 __attribute__((ext_vector_type(8)));

#define MFMA_BF16(a, b, c) __builtin_amdgcn_mfma_f32_16x16x32_bf16((a), (b), (c), 0, 0, 0)

// Problem constants: B=8, T=2048, D=1024, HS=64; scale = 1/sqrt(2048) (per reference!)

__device__ __forceinline__ u16 f2bf(float f) {
  union { float f; u32 u; } v; v.f = f;
  u32 u = v.u;
  return (u16)((u + 0x7FFFu + ((u >> 16) & 1u)) >> 16);  // RNE f32->bf16
}
__device__ __forceinline__ u16 f2bf_t(float f) {  // truncating f32->bf16 (P tile only)
  union { float f; u32 u; } v; v.f = f;
  return (u16)(v.u >> 16);
}
__device__ __forceinline__ s16x8 pack_bf8(float4 a, float4 b) {
  union { u32 d[4]; s16x8 v; } u;
  u.d[0] = (u32)f2bf(a.x) | ((u32)f2bf(a.y) << 16);
  u.d[1] = (u32)f2bf(a.z) | ((u32)f2bf(a.w) << 16);
  u.d[2] = (u32)f2bf(b.x) | ((u32)f2bf(b.y) << 16);
  u.d[3] = (u32)f2bf(b.z) | ((u32)f2bf(b.w) << 16);
  return u.v;
}
__device__ __forceinline__ void gload_lds16(const void* g, void* l) {
  __builtin_amdgcn_global_load_lds((const __attribute__((address_space(1))) u32*)g,
                                   (__attribute__((address_space(3))) u32*)l, 16, 0, 0);
}

// ---- Kernel 1: W [1024][64] f32 x3 -> Wt3 bf16 [16 kstep][192 row][64 k]
// (rows: q 0-63, k 64-127, v 128-191). Each k-step's W is one contiguous 24KB chunk.
__global__ __launch_bounds__(256) void wt_convert(const float* __restrict__ Wq,
                                                  const float* __restrict__ Wk,
                                                  const float* __restrict__ Wv,
                                                  u16* __restrict__ Wt3) {
  __shared__ u16 Ls[64][70];
  const int bid = blockIdx.x;
  const int m = bid >> 4, kstep = bid & 15, d0 = kstep * 64;
  const float* W = (m == 0) ? Wq : (m == 1) ? Wk : Wv;
  const int t = threadIdx.x;
  {
    const int dr = t >> 2, hc = (t & 3) * 16;
    const float4* src = (const float4*)(W + (size_t)(d0 + dr) * 64 + hc);
    float4 f0 = src[0], f1 = src[1], f2 = src[2], f3 = src[3];
    float fl[16] = {f0.x, f0.y, f0.z, f0.w, f1.x, f1.y, f1.z, f1.w,
                    f2.x, f2.y, f2.z, f2.w, f3.x, f3.y, f3.z, f3.w};
#pragma unroll
    for (int j = 0; j < 8; ++j) {
      u32 pk = (u32)f2bf(fl[2 * j]) | ((u32)f2bf(fl[2 * j + 1]) << 16);
      *(u32*)&Ls[dr][hc + 2 * j] = pk;
    }
  }
  __syncthreads();
  {
    const int h = t >> 2, dcs = (t & 3) * 16;
    const int grow = m * 64 + h;
    u32 po[8];
#pragma unroll
    for (int j = 0; j < 8; ++j)
      po[j] = (u32)Ls[dcs + 2 * j][h] | ((u32)Ls[dcs + 2 * j + 1][h] << 16);
    u16* dst = Wt3 + (size_t)kstep * 12288 + grow * 64 + dcs;
    *(uint4*)&dst[0] = make_uint4(po[0], po[1], po[2], po[3]);
    *(uint4*)&dst[8] = make_uint4(po[4], po[5], po[6], po[7]);
  }
}

// ---- Kernel 2: QKV projection. C[16384,192] = X[16384,1024] @ W[1024,192], bf16 MFMA.
// BM=64, BK=64, 1024 threads (16 waves), grid 256 = 1 block/CU = 4 waves/SIMD.
// Wave (msub=w&3, ntg=w>>2): 16 rows x 3 n-tiles over FULL K -> acc[3] (12 regs),
// NO k-split merge. W L2 re-read traffic halved vs BM=32 (98 MB total).
// BOTH X (as f32) and W staged via global_load_lds (zero VGPR staging); bf16 pack
// at A-read time. Granule-XOR swizzle both sides: X g16^=(row&15), W g8^=(row&7)
// -> all LDS reads 2-way on banks (free). One barrier per k-step, 2-phase prefetch.
__global__ __launch_bounds__(1024) void qkv_gemm(const float* __restrict__ x,
                                                 const u16* __restrict__ Wt3,
                                                 u16* __restrict__ qo,
                                                 u16* __restrict__ ko,
                                                 u16* __restrict__ vTo) {
  __shared__ float Xf[2][4096];   // [64 row][64 f32] 256B rows, swizzled (32 KB)
  __shared__ u16 Wl[2][12288];    // [192 row][64 bf16] 128B rows, swizzled (48 KB)
  const int tid = threadIdx.x, lane = tid & 63, w = tid >> 6;
  const int lc = lane & 15, hi = lane >> 4;
  const int m0 = blockIdx.x * 64;
  const int msub = w & 3, ntg = w >> 2;  // 4 m-subtiles x 4 n-groups

  f32x4 acc[3];
#pragma unroll
  for (int i = 0; i < 3; ++i) acc[i] = (f32x4){0.f, 0.f, 0.f, 0.f};

  // X staging: wave w stages rows 4w..4w+3 (1KB). lane l -> row 4w+(l>>4),
  // source granule (l&15)^(row&15)  (inverse of read swizzle).
  const int rX = w * 4 + (lane >> 4);
  const int gX = (lane & 15) ^ (rX & 15);
  const float* xsrc = x + (size_t)(m0 + rX) * 1024 + gX * 4;
  // W staging: instr j covers rows 8j..8j+7; wave w issues j=w and (w<8) j=16+w.
  const int rW = w * 8 + (lane >> 3);
  const int gW = (lane & 7) ^ (rW & 7);
  const u16* wsrc = Wt3 + rW * 64 + gW * 8;  // j=16+w source = wsrc + 8192

  auto stage = [&](int t, int bf) {
    gload_lds16(xsrc + t * 64, &Xf[bf][w * 256]);
    gload_lds16(wsrc + (size_t)t * 12288, &Wl[bf][w * 512]);
    if (w < 8) gload_lds16(wsrc + (size_t)t * 12288 + 8192, &Wl[bf][(16 + w) * 512]);
  };

  stage(0, 0);
  __syncthreads();
  int buf = 0;

  const int rA = msub * 16 + lc;
  for (int t = 0; t < 16; ++t) {
    if (t < 15) stage(t + 1, buf ^ 1);
#pragma unroll
    for (int ksub = 0; ksub < 2; ++ksub) {
      const int g0 = ksub * 8 + hi * 2;
      float4 alo = *(const float4*)&Xf[buf][rA * 64 + ((g0 ^ (rA & 15)) << 2)];
      float4 ahi = *(const float4*)&Xf[buf][rA * 64 + (((g0 + 1) ^ (rA & 15)) << 2)];
      s16x8 a = pack_bf8(alo, ahi);
#pragma unroll
      for (int j = 0; j < 3; ++j) {
        const int rB = (ntg * 3 + j) * 16 + lc;
        const int gB = (ksub * 4 + hi) ^ (rB & 7);
        s16x8 b = *(const s16x8*)&Wl[buf][rB * 64 + gB * 8];
        acc[j] = MFMA_BF16(a, b, acc[j]);
      }
    }
    if (t < 15) {
      __syncthreads();
      buf ^= 1;
    }
  }

  // epilogue: C layout col=lane&15, row=(lane>>4)*4+r; no k-merge needed.
#pragma unroll
  for (int j = 0; j < 3; ++j) {
    const int nt = ntg * 3 + j;
#pragma unroll
    for (int r = 0; r < 4; ++r) {
      const int gr = m0 + msub * 16 + hi * 4 + r;
      const u16 val = f2bf(acc[j][r]);
      const int n = nt * 16 + lc;
      if (nt < 4) {
        qo[gr * 64 + n] = val;
      } else if (nt < 8) {
        ko[gr * 64 + (n - 64)] = val;
      } else {
        int b = gr >> 11, t2 = gr & 2047;
        vTo[((b << 6) + (n - 128)) * 2048 + t2] = val;
      }
    }
  }
}

// ---- Kernel 3: causal flash attention, no-max softmax. 256 threads = 4 waves.
// (unchanged from round 5/7: ~10us)
__global__ __launch_bounds__(256, 2) void attn_fwd(const u16* __restrict__ qb,
                                                   const u16* __restrict__ kb,
                                                   const u16* __restrict__ vT,
                                                   float* __restrict__ out) {
  __shared__ float PoS[4][32][66];  // per-wave merge buffer; P tile [32][40]u16 unioned in
  __shared__ float Pl[4][32];       // per-wave denominator partials
  const int tid = threadIdx.x, lane = tid & 63, w = tid >> 6;
  const int lc = lane & 15, hi = lane >> 4;
  const int bid = blockIdx.x;
  const int b = bid & 7, v = 63 - (bid >> 3);  // batch, q-tile id (heavy-first)
  const int q0 = v * 32;                       // q-tile base row within batch
  const int brow = b * 2048;
  u16* Pw = (u16*)&PoS[w][0][0];  // [32][40] u16 view, per-wave

  s16x8 aq[2][2];
#pragma unroll
  for (int sub = 0; sub < 2; ++sub) {
    const u16* qrow = qb + (size_t)(brow + q0 + sub * 16 + lc) * 64;
    aq[sub][0] = *(const s16x8*)(qrow + hi * 8);
    aq[sub][1] = *(const s16x8*)(qrow + 32 + hi * 8);
  }

  f32x4 o[2][4];
  float lrow[2][4];
#pragma unroll
  for (int sub = 0; sub < 2; ++sub)
#pragma unroll
    for (int i = 0; i < 4; ++i) {
      o[sub][i] = (f32x4){0.f, 0.f, 0.f, 0.f};
      lrow[sub][i] = 0.f;
    }

  const float SL = 0.031879357f;  // (1/sqrt(2048)) * log2(e)
  const int nk = v + 1;           // causal kv-tiles of 32 for this q-tile
  const int c = (nk + 3) >> 2;    // chunk per split-wave (4-way)
  const int s = w;
  const int it0 = s * c;
  const int it1 = min(it0 + c, nk);

  const u16* kbase = kb + (size_t)brow * 64;

  for (int it = it0; it < it1; ++it) {
    const int kvb = it * 32;
    const u16* krow0 = kbase + (size_t)(kvb + lc) * 64;
    const u16* krow1 = kbase + (size_t)(kvb + 16 + lc) * 64;
    s16x8 k00 = *(const s16x8*)(krow0 + hi * 8);
    s16x8 k01 = *(const s16x8*)(krow0 + 32 + hi * 8);
    s16x8 k10 = *(const s16x8*)(krow1 + hi * 8);
    s16x8 k11 = *(const s16x8*)(krow1 + 32 + hi * 8);
    s16x8 bv[4];
#pragma unroll
    for (int nt = 0; nt < 4; ++nt)
      bv[nt] = *(const s16x8*)&vT[(size_t)(b * 64 + nt * 16 + lc) * 2048 + kvb + hi * 8];

    f32x4 sc[2][2];
#pragma unroll
    for (int sub = 0; sub < 2; ++sub) {
      sc[sub][0] = (f32x4){0.f, 0.f, 0.f, 0.f};
      sc[sub][1] = (f32x4){0.f, 0.f, 0.f, 0.f};
      sc[sub][0] = MFMA_BF16(aq[sub][0], k00, sc[sub][0]);
      sc[sub][0] = MFMA_BF16(aq[sub][1], k01, sc[sub][0]);
      sc[sub][1] = MFMA_BF16(aq[sub][0], k10, sc[sub][1]);
      sc[sub][1] = MFMA_BF16(aq[sub][1], k11, sc[sub][1]);
    }

    if (kvb + 31 <= q0) {  // tile fully below diagonal: no masks
#pragma unroll
      for (int sub = 0; sub < 2; ++sub)
#pragma unroll
        for (int r = 0; r < 4; ++r) {
          float p0 = exp2f(sc[sub][0][r] * SL);
          float p1 = exp2f(sc[sub][1][r] * SL);
          lrow[sub][r] += p0 + p1;
          Pw[(sub * 16 + hi * 4 + r) * 40 + lc] = f2bf_t(p0);
          Pw[(sub * 16 + hi * 4 + r) * 40 + 16 + lc] = f2bf_t(p1);
        }
    } else {  // diagonal tile: causal masks
#pragma unroll
      for (int sub = 0; sub < 2; ++sub)
#pragma unroll
        for (int r = 0; r < 4; ++r) {
          const int qt = q0 + sub * 16 + hi * 4 + r;
          const int kv0 = kvb + lc;
          float p0 = (kv0 <= qt) ? exp2f(sc[sub][0][r] * SL) : 0.f;
          float p1 = (kv0 + 16 <= qt) ? exp2f(sc[sub][1][r] * SL) : 0.f;
          lrow[sub][r] += p0 + p1;
          Pw[(sub * 16 + hi * 4 + r) * 40 + lc] = f2bf_t(p0);
          Pw[(sub * 16 + hi * 4 + r) * 40 + 16 + lc] = f2bf_t(p1);
        }
    }
    asm volatile("s_waitcnt lgkmcnt(0)" ::: "memory");
    s16x8 pa0 = *(const s16x8*)&Pw[lc * 40 + hi * 8];
    s16x8 pa1 = *(const s16x8*)&Pw[(16 + lc) * 40 + hi * 8];
#pragma unroll
    for (int nt = 0; nt < 4; ++nt) {
      o[0][nt] = MFMA_BF16(pa0, bv[nt], o[0][nt]);
      o[1][nt] = MFMA_BF16(pa1, bv[nt], o[1][nt]);
    }
  }

#pragma unroll
  for (int sub = 0; sub < 2; ++sub)
#pragma unroll
    for (int r = 0; r < 4; ++r) {
      float l = lrow[sub][r];
      l += __shfl_xor(l, 1);
      l += __shfl_xor(l, 2);
      l += __shfl_xor(l, 4);
      l += __shfl_xor(l, 8);
      lrow[sub][r] = l;
    }

  if (lc == 0) {
#pragma unroll
    for (int sub = 0; sub < 2; ++sub)
#pragma unroll
      for (int r = 0; r < 4; ++r) Pl[w][sub * 16 + hi * 4 + r] = lrow[sub][r];
  }
  float* Pow = &PoS[w][0][0];
#pragma unroll
  for (int sub = 0; sub < 2; ++sub)
#pragma unroll
    for (int nt = 0; nt < 4; ++nt)
#pragma unroll
      for (int r = 0; r < 4; ++r)
        Pow[(sub * 16 + hi * 4 + r) * 66 + nt * 16 + lc] = o[sub][nt][r];
  __syncthreads();

#pragma unroll
  for (int rr = 0; rr < 8; ++rr) {
    const int row = w * 8 + rr;
    float L = Pl[0][row] + Pl[1][row] + Pl[2][row] + Pl[3][row];
    float val = PoS[0][row][lane] + PoS[1][row][lane] + PoS[2][row][lane] + PoS[3][row][lane];
    out[(size_t)(brow + q0 + row) * 64 + lane] = val / L;
  }
}

extern "C" void kernel_launch(void* const* d_in, const int* in_sizes, int n_in,
                              void* d_out, int out_size, void* d_ws, size_t ws_size,
                              hipStream_t stream) {
  (void)in_sizes; (void)n_in; (void)out_size; (void)ws_size;
  const float* x = (const float*)d_in[0];
  const float* Wq = (const float*)d_in[1];
  const float* Wk = (const float*)d_in[2];
  const float* Wv = (const float*)d_in[3];
  float* out = (float*)d_out;

  u16* wsu = (u16*)d_ws;
  u16* Wt = wsu;                      // 16*192*64 = 196608 (k-step-major layout)
  u16* qb = Wt + 192 * 1024;          // 8*2048*64
  u16* kb = qb + 8 * 2048 * 64;       // 8*2048*64
  u16* vT = kb + 8 * 2048 * 64;       // 8*64*2048
  // total ws use: 6,684,672 bytes

  wt_convert<<<48, 256, 0, stream>>>(Wq, Wk, Wv, Wt);
  qkv_gemm<<<256, 1024, 0, stream>>>(x, Wt, qb, kb, vT);
  attn_fwd<<<512, 256, 0, stream>>>(qb, kb, vT, out);
}

// Round 10
// 57.321 us; speedup vs baseline: 1.0259x; 1.0259x over previous
//
#include <hip/hip_runtime.h>

typedef unsigned short u16;
typedef unsigned int u32;
typedef float f32x4 __attribute__((ext_vector_type(4)));
typedef short s16x8 __attribute__((ext_vector_type(8)));

#define MFMA_BF16(a, b, c) __builtin_amdgcn_mfma_f32_16x16x32_bf16((a), (b), (c), 0, 0, 0)

// Problem constants: B=8, T=2048, D=1024, HS=64; scale = 1/sqrt(2048) (per reference!)

__device__ __forceinline__ u16 f2bf(float f) {
  union { float f; u32 u; } v; v.f = f;
  u32 u = v.u;
  return (u16)((u + 0x7FFFu + ((u >> 16) & 1u)) >> 16);  // RNE f32->bf16
}
__device__ __forceinline__ u16 f2bf_t(float f) {  // truncating f32->bf16 (P tile only)
  union { float f; u32 u; } v; v.f = f;
  return (u16)(v.u >> 16);
}
__device__ __forceinline__ s16x8 pack_bf8(float4 a, float4 b) {
  union { u32 d[4]; s16x8 v; } u;
  u.d[0] = (u32)f2bf(a.x) | ((u32)f2bf(a.y) << 16);
  u.d[1] = (u32)f2bf(a.z) | ((u32)f2bf(a.w) << 16);
  u.d[2] = (u32)f2bf(b.x) | ((u32)f2bf(b.y) << 16);
  u.d[3] = (u32)f2bf(b.z) | ((u32)f2bf(b.w) << 16);
  return u.v;
}
__device__ __forceinline__ void gload_lds16(const void* g, void* l) {
  __builtin_amdgcn_global_load_lds((const __attribute__((address_space(1))) u32*)g,
                                   (__attribute__((address_space(3))) u32*)l, 16, 0, 0);
}

// ---- Kernel 1: W [1024][64] f32 x3 -> Wt3 bf16 [32 kstep][192 row][32 k]
// (rows: q 0-63, k 64-127, v 128-191). Each k-step's W = one contiguous 12KB chunk.
__global__ __launch_bounds__(256) void wt_convert(const float* __restrict__ Wq,
                                                  const float* __restrict__ Wk,
                                                  const float* __restrict__ Wv,
                                                  u16* __restrict__ Wt3) {
  __shared__ u16 Ls[64][70];
  const int bid = blockIdx.x;
  const int m = bid >> 4, d0 = (bid & 15) * 64;
  const float* W = (m == 0) ? Wq : (m == 1) ? Wk : Wv;
  const int t = threadIdx.x;
  {
    const int dr = t >> 2, hc = (t & 3) * 16;
    const float4* src = (const float4*)(W + (size_t)(d0 + dr) * 64 + hc);
    float4 f0 = src[0], f1 = src[1], f2 = src[2], f3 = src[3];
    float fl[16] = {f0.x, f0.y, f0.z, f0.w, f1.x, f1.y, f1.z, f1.w,
                    f2.x, f2.y, f2.z, f2.w, f3.x, f3.y, f3.z, f3.w};
#pragma unroll
    for (int j = 0; j < 8; ++j) {
      u32 pk = (u32)f2bf(fl[2 * j]) | ((u32)f2bf(fl[2 * j + 1]) << 16);
      *(u32*)&Ls[dr][hc + 2 * j] = pk;
    }
  }
  __syncthreads();
  {
    const int h = t >> 2, dcs = (t & 3) * 16;
    const int grow = m * 64 + h;
    const int dd = d0 + dcs;
    u32 po[8];
#pragma unroll
    for (int j = 0; j < 8; ++j)
      po[j] = (u32)Ls[dcs + 2 * j][h] | ((u32)Ls[dcs + 2 * j + 1][h] << 16);
    u16* dst = Wt3 + ((size_t)(dd >> 5) * 192 + grow) * 32 + (dd & 31);
    *(uint4*)&dst[0] = make_uint4(po[0], po[1], po[2], po[3]);
    *(uint4*)&dst[8] = make_uint4(po[4], po[5], po[6], po[7]);
  }
}

// ---- Kernel 2: QKV projection. C[16384,192] = X[16384,1024] @ W[1024,192], bf16 MFMA.
// COUNTED-VMCNT pipeline (guide T3+T4): BK=32, 32 steps, 4 LDS buffers, depth-3
// prefetch. Raw s_barrier + per-wave literal vmcnt(2k) -- NEVER drained to 0 in the
// main loop, so 3 batches of global_load_lds stay in flight across every barrier.
// 1024 thr (16 waves = 4 msub x 4 ntg), BM=64, grid 256 (1 block/CU), acc[3]/wave.
// Per-step per-wave loads: w0-3: X+W (2), w4-7: X (1), w8-15: W (1).
// Swizzles (both-sides, rule #21): X granule16 g^=(row&7); W g^=(row&3)^((row>>2)&3)
// -> all LDS reads 2-way per 16-lane phase (free). Staging dest linear (gload_lds).
__global__ __launch_bounds__(1024) void qkv_gemm(const float* __restrict__ x,
                                                 const u16* __restrict__ Wt3,
                                                 u16* __restrict__ qo,
                                                 u16* __restrict__ ko,
                                                 u16* __restrict__ vTo) {
  __shared__ float Xf[4][2048];  // 4 x [64 row][32 k] f32 (8KB/buf), swizzled
  __shared__ u16 Wl[4][6144];    // 4 x [192 row][32 k] bf16 (12KB/buf), swizzled
  const int tid = threadIdx.x, lane = tid & 63, w = tid >> 6;
  const int lc = lane & 15, hi = lane >> 4;
  const int m0 = blockIdx.x * 64;
  const int msub = w & 3, ntg = w >> 2;

  f32x4 acc[3];
#pragma unroll
  for (int i = 0; i < 3; ++i) acc[i] = (f32x4){0.f, 0.f, 0.f, 0.f};

  // X staging (waves 0-7): instr i=w covers rows 8w..8w+7; lane l -> row 8w+(l>>3),
  // dest granule l&7; source granule = (l&7)^(row&7) = (l&7)^((l>>3)&7).
  const int xrow = (w & 7) * 8 + (lane >> 3);
  const int xg = (lane & 7) ^ ((lane >> 3) & 7);
  const float* xsrc = x + (size_t)(m0 + xrow) * 1024 + xg * 4;
  // W staging: instr j covers rows 16j..16j+15; waves 8-15: j=w-8, waves 0-3: j=8+w.
  // lane l -> row 16j+(l>>2), dest granule l&3; src granule = (l&3)^((l>>2)&3)^((l>>4)&3).
  const int j1 = (w >= 8) ? (w - 8) : (8 + w);
  const int wrow1 = j1 * 16 + (lane >> 2);
  const int gW = (lane & 3) ^ ((lane >> 2) & 3) ^ ((lane >> 4) & 3);
  const u16* wsrc = Wt3 + wrow1 * 32 + gW * 8;
  const bool sx = (w < 8), sw = (w >= 8) || (w < 4);

  auto stage = [&](int t, int bf) {
    if (sx) gload_lds16(xsrc + (size_t)t * 32, &Xf[bf][(w & 7) * 256]);
    if (sw) gload_lds16(wsrc + (size_t)t * 6144, &Wl[bf][j1 * 512]);
  };

  // read offsets (element units), swizzled
  const int rA = msub * 16 + lc;
  const int aof0 = rA * 32 + ((((hi * 2)) ^ (rA & 7)) << 2);
  const int aof1 = rA * 32 + ((((hi * 2) + 1) ^ (rA & 7)) << 2);
  int bof[3];
#pragma unroll
  for (int j = 0; j < 3; ++j) {
    const int rB = (ntg * 3 + j) * 16 + lc;
    const int slot = hi ^ (rB & 3) ^ ((rB >> 2) & 3);
    bof[j] = rB * 32 + slot * 8;
  }

  // prologue: 3 batches in flight
  stage(0, 0);
  stage(1, 1);
  stage(2, 2);

  for (int t = 0; t < 32; ++t) {
    // wait for MY batch-t loads only (2 or 3 batches stay outstanding)
    if (t <= 29) {
      if (w < 4) asm volatile("s_waitcnt vmcnt(4)" ::: "memory");
      else       asm volatile("s_waitcnt vmcnt(2)" ::: "memory");
    } else if (t == 30) {
      if (w < 4) asm volatile("s_waitcnt vmcnt(2)" ::: "memory");
      else       asm volatile("s_waitcnt vmcnt(1)" ::: "memory");
    } else {
      asm volatile("s_waitcnt vmcnt(0)" ::: "memory");
    }
    asm volatile("s_waitcnt lgkmcnt(0)" ::: "memory");
    __builtin_amdgcn_s_barrier();          // raw barrier: NO vmcnt(0) drain
    __builtin_amdgcn_sched_barrier(0);
    const int bf = t & 3;
    float4 alo = *(const float4*)&Xf[bf][aof0];
    float4 ahi = *(const float4*)&Xf[bf][aof1];
    s16x8 a = pack_bf8(alo, ahi);
#pragma unroll
    for (int j = 0; j < 3; ++j) {
      s16x8 bfr = *(const s16x8*)&Wl[bf][bof[j]];
      acc[j] = MFMA_BF16(a, bfr, acc[j]);
    }
    if (t < 29) stage(t + 3, (t + 3) & 3);  // after barrier: prior readers done
  }

  // epilogue: C layout col=lane&15, row=(lane>>4)*4+r; full K per wave, no merge.
#pragma unroll
  for (int j = 0; j < 3; ++j) {
    const int nt = ntg * 3 + j;
#pragma unroll
    for (int r = 0; r < 4; ++r) {
      const int gr = m0 + msub * 16 + hi * 4 + r;
      const u16 val = f2bf(acc[j][r]);
      const int n = nt * 16 + lc;
      if (nt < 4) {
        qo[gr * 64 + n] = val;
      } else if (nt < 8) {
        ko[gr * 64 + (n - 64)] = val;
      } else {
        int b = gr >> 11, t2 = gr & 2047;
        vTo[((b << 6) + (n - 128)) * 2048 + t2] = val;
      }
    }
  }
}

// ---- Kernel 3: causal flash attention, no-max softmax. 256 threads = 4 waves.
// (unchanged from round 5/7: ~10us)
__global__ __launch_bounds__(256, 2) void attn_fwd(const u16* __restrict__ qb,
                                                   const u16* __restrict__ kb,
                                                   const u16* __restrict__ vT,
                                                   float* __restrict__ out) {
  __shared__ float PoS[4][32][66];  // per-wave merge buffer; P tile [32][40]u16 unioned in
  __shared__ float Pl[4][32];       // per-wave denominator partials
  const int tid = threadIdx.x, lane = tid & 63, w = tid >> 6;
  const int lc = lane & 15, hi = lane >> 4;
  const int bid = blockIdx.x;
  const int b = bid & 7, v = 63 - (bid >> 3);  // batch, q-tile id (heavy-first)
  const int q0 = v * 32;                       // q-tile base row within batch
  const int brow = b * 2048;
  u16* Pw = (u16*)&PoS[w][0][0];  // [32][40] u16 view, per-wave

  s16x8 aq[2][2];
#pragma unroll
  for (int sub = 0; sub < 2; ++sub) {
    const u16* qrow = qb + (size_t)(brow + q0 + sub * 16 + lc) * 64;
    aq[sub][0] = *(const s16x8*)(qrow + hi * 8);
    aq[sub][1] = *(const s16x8*)(qrow + 32 + hi * 8);
  }

  f32x4 o[2][4];
  float lrow[2][4];
#pragma unroll
  for (int sub = 0; sub < 2; ++sub)
#pragma unroll
    for (int i = 0; i < 4; ++i) {
      o[sub][i] = (f32x4){0.f, 0.f, 0.f, 0.f};
      lrow[sub][i] = 0.f;
    }

  const float SL = 0.031879357f;  // (1/sqrt(2048)) * log2(e)
  const int nk = v + 1;           // causal kv-tiles of 32 for this q-tile
  const int c = (nk + 3) >> 2;    // chunk per split-wave (4-way)
  const int s = w;
  const int it0 = s * c;
  const int it1 = min(it0 + c, nk);

  const u16* kbase = kb + (size_t)brow * 64;

  for (int it = it0; it < it1; ++it) {
    const int kvb = it * 32;
    const u16* krow0 = kbase + (size_t)(kvb + lc) * 64;
    const u16* krow1 = kbase + (size_t)(kvb + 16 + lc) * 64;
    s16x8 k00 = *(const s16x8*)(krow0 + hi * 8);
    s16x8 k01 = *(const s16x8*)(krow0 + 32 + hi * 8);
    s16x8 k10 = *(const s16x8*)(krow1 + hi * 8);
    s16x8 k11 = *(const s16x8*)(krow1 + 32 + hi * 8);
    s16x8 bv[4];
#pragma unroll
    for (int nt = 0; nt < 4; ++nt)
      bv[nt] = *(const s16x8*)&vT[(size_t)(b * 64 + nt * 16 + lc) * 2048 + kvb + hi * 8];

    f32x4 sc[2][2];
#pragma unroll
    for (int sub = 0; sub < 2; ++sub) {
      sc[sub][0] = (f32x4){0.f, 0.f, 0.f, 0.f};
      sc[sub][1] = (f32x4){0.f, 0.f, 0.f, 0.f};
      sc[sub][0] = MFMA_BF16(aq[sub][0], k00, sc[sub][0]);
      sc[sub][0] = MFMA_BF16(aq[sub][1], k01, sc[sub][0]);
      sc[sub][1] = MFMA_BF16(aq[sub][0], k10, sc[sub][1]);
      sc[sub][1] = MFMA_BF16(aq[sub][1], k11, sc[sub][1]);
    }

    if (kvb + 31 <= q0) {  // tile fully below diagonal: no masks
#pragma unroll
      for (int sub = 0; sub < 2; ++sub)
#pragma unroll
        for (int r = 0; r < 4; ++r) {
          float p0 = exp2f(sc[sub][0][r] * SL);
          float p1 = exp2f(sc[sub][1][r] * SL);
          lrow[sub][r] += p0 + p1;
          Pw[(sub * 16 + hi * 4 + r) * 40 + lc] = f2bf_t(p0);
          Pw[(sub * 16 + hi * 4 + r) * 40 + 16 + lc] = f2bf_t(p1);
        }
    } else {  // diagonal tile: causal masks
#pragma unroll
      for (int sub = 0; sub < 2; ++sub)
#pragma unroll
        for (int r = 0; r < 4; ++r) {
          const int qt = q0 + sub * 16 + hi * 4 + r;
          const int kv0 = kvb + lc;
          float p0 = (kv0 <= qt) ? exp2f(sc[sub][0][r] * SL) : 0.f;
          float p1 = (kv0 + 16 <= qt) ? exp2f(sc[sub][1][r] * SL) : 0.f;
          lrow[sub][r] += p0 + p1;
          Pw[(sub * 16 + hi * 4 + r) * 40 + lc] = f2bf_t(p0);
          Pw[(sub * 16 + hi * 4 + r) * 40 + 16 + lc] = f2bf_t(p1);
        }
    }
    asm volatile("s_waitcnt lgkmcnt(0)" ::: "memory");
    s16x8 pa0 = *(const s16x8*)&Pw[lc * 40 + hi * 8];
    s16x8 pa1 = *(const s16x8*)&Pw[(16 + lc) * 40 + hi * 8];
#pragma unroll
    for (int nt = 0; nt < 4; ++nt) {
      o[0][nt] = MFMA_BF16(pa0, bv[nt], o[0][nt]);
      o[1][nt] = MFMA_BF16(pa1, bv[nt], o[1][nt]);
    }
  }

#pragma unroll
  for (int sub = 0; sub < 2; ++sub)
#pragma unroll
    for (int r = 0; r < 4; ++r) {
      float l = lrow[sub][r];
      l += __shfl_xor(l, 1);
      l += __shfl_xor(l, 2);
      l += __shfl_xor(l, 4);
      l += __shfl_xor(l, 8);
      lrow[sub][r] = l;
    }

  if (lc == 0) {
#pragma unroll
    for (int sub = 0; sub < 2; ++sub)
#pragma unroll
      for (int r = 0; r < 4; ++r) Pl[w][sub * 16 + hi * 4 + r] = lrow[sub][r];
  }
  float* Pow = &PoS[w][0][0];
#pragma unroll
  for (int sub = 0; sub < 2; ++sub)
#pragma unroll
    for (int nt = 0; nt < 4; ++nt)
#pragma unroll
      for (int r = 0; r < 4; ++r)
        Pow[(sub * 16 + hi * 4 + r) * 66 + nt * 16 + lc] = o[sub][nt][r];
  __syncthreads();

#pragma unroll
  for (int rr = 0; rr < 8; ++rr) {
    const int row = w * 8 + rr;
    float L = Pl[0][row] + Pl[1][row] + Pl[2][row] + Pl[3][row];
    float val = PoS[0][row][lane] + PoS[1][row][lane] + PoS[2][row][lane] + PoS[3][row][lane];
    out[(size_t)(brow + q0 + row) * 64 + lane] = val / L;
  }
}

extern "C" void kernel_launch(void* const* d_in, const int* in_sizes, int n_in,
                              void* d_out, int out_size, void* d_ws, size_t ws_size,
                              hipStream_t stream) {
  (void)in_sizes; (void)n_in; (void)out_size; (void)ws_size;
  const float* x = (const float*)d_in[0];
  const float* Wq = (const float*)d_in[1];
  const float* Wk = (const float*)d_in[2];
  const float* Wv = (const float*)d_in[3];
  float* out = (float*)d_out;

  u16* wsu = (u16*)d_ws;
  u16* Wt = wsu;                      // 32*192*32 = 196608 (k-step-major layout)
  u16* qb = Wt + 192 * 1024;          // 8*2048*64
  u16* kb = qb + 8 * 2048 * 64;       // 8*2048*64
  u16* vT = kb + 8 * 2048 * 64;       // 8*64*2048
  // total ws use: 6,684,672 bytes

  wt_convert<<<48, 256, 0, stream>>>(Wq, Wk, Wv, Wt);
  qkv_gemm<<<256, 1024, 0, stream>>>(x, Wt, qb, kb, vT);
  attn_fwd<<<512, 256, 0, stream>>>(qb, kb, vT, out);
}